// Round 1
// 1258.222 us; speedup vs baseline: 1.3033x; 1.3033x over previous
//
#include <hip/hip_runtime.h>

#define N_NODES 100000
#define N_EDGES 1600000
#define DIM_IN  256
#define DIM_HID 128
#define DIM_OUT 64

// ---------------- GEMM: C = act(A @ W + bias) ----------------
// 128x64 tile, BK=32, 256 threads, 8x4 acc/thread.
// A-tile stored transposed [BK][BM] with XOR swizzle m ^ ((kk>>2)<<3):
//   staging writes (stride-512B) and compute reads are both <=2-way bank aliased.
#define BM 128
#define BN 64
#define BK 32

__global__ __launch_bounds__(256, 4) void gemm_bias_act(
    const float* __restrict__ A, const float* __restrict__ W,
    const float* __restrict__ bias, float* __restrict__ C,
    int M, int K, int F, int do_relu)
{
    __shared__ float As[BK][BM];   // swizzled
    __shared__ float Ws[BK][BN];
    const int tid = threadIdx.x;
    const int tx = tid & 15;        // n: 4 cols each
    const int ty = tid >> 4;        // m: 8 rows each
    const int bm = blockIdx.x * BM;
    const int bn = blockIdx.y * BN;

    const int am  = tid >> 3;       // A staging: row 0..31 (+32*it)
    const int akq = tid & 7;        // A staging: float4 index within 32-k row
    const int wr  = tid >> 4;       // W staging: row 0..15 (+16*it)
    const int wcq = tid & 15;       // W staging: float4 col

    float acc[8][4] = {};

    for (int k0 = 0; k0 < K; k0 += BK) {
        // stage A tile (128 rows x 32 k), transposed + swizzled
        #pragma unroll
        for (int it = 0; it < 4; ++it) {
            int m = am + it * 32;
            int gm = bm + m;
            float4 a4 = make_float4(0.f, 0.f, 0.f, 0.f);
            if (gm < M)
                a4 = *(const float4*)&A[(size_t)gm * K + k0 + akq * 4];
            int msw = m ^ (akq << 3);          // akq == kk>>2 for kk in [akq*4, akq*4+3]
            As[akq * 4 + 0][msw] = a4.x;
            As[akq * 4 + 1][msw] = a4.y;
            As[akq * 4 + 2][msw] = a4.z;
            As[akq * 4 + 3][msw] = a4.w;
        }
        // stage W tile (32 x 64)
        #pragma unroll
        for (int it = 0; it < 2; ++it) {
            int r = wr + it * 16;
            float4 w4 = *(const float4*)&W[(size_t)(k0 + r) * F + bn + wcq * 4];
            *(float4*)&Ws[r][wcq * 4] = w4;
        }
        __syncthreads();
        #pragma unroll
        for (int kk = 0; kk < BK; ++kk) {
            const float* ap = &As[kk][(ty * 8) ^ (((kk >> 2) & 7) << 3)];
            float4 a0 = *(const float4*)(ap);
            float4 a1 = *(const float4*)(ap + 4);
            float4 w4 = *(const float4*)&Ws[kk][tx * 4];
            float a[8] = {a0.x, a0.y, a0.z, a0.w, a1.x, a1.y, a1.z, a1.w};
            float w[4] = {w4.x, w4.y, w4.z, w4.w};
            #pragma unroll
            for (int i = 0; i < 8; ++i)
                #pragma unroll
                for (int j = 0; j < 4; ++j)
                    acc[i][j] = fmaf(a[i], w[j], acc[i][j]);
        }
        __syncthreads();
    }
    float4 b4 = *(const float4*)&bias[bn + tx * 4];
    #pragma unroll
    for (int i = 0; i < 8; ++i) {
        int m = bm + ty * 8 + i;
        if (m < M) {
            float4 v;
            v.x = acc[i][0] + b4.x;
            v.y = acc[i][1] + b4.y;
            v.z = acc[i][2] + b4.z;
            v.w = acc[i][3] + b4.w;
            if (do_relu) {
                v.x = fmaxf(v.x, 0.f); v.y = fmaxf(v.y, 0.f);
                v.z = fmaxf(v.z, 0.f); v.w = fmaxf(v.w, 0.f);
            }
            *(float4*)&C[(size_t)m * F + bn + tx * 4] = v;
        }
    }
}

// ---------------- degree ----------------
__global__ void zero_int_kernel(int* __restrict__ p, int n) {
    int i = blockIdx.x * blockDim.x + threadIdx.x;
    if (i < n) p[i] = 0;
}

// deg layout: [0,N) = outdeg (row), [N,2N) = indeg (col)
__global__ void degree_kernel(const int* __restrict__ row, const int* __restrict__ col,
                              int* __restrict__ deg, int E, int N) {
    int e = blockIdx.x * blockDim.x + threadIdx.x;
    if (e < E) {
        atomicAdd(&deg[row[e]], 1);
        atomicAdd(&deg[N + col[e]], 1);
    }
}

__global__ void inv_kernel(const int* __restrict__ deg,
                           float* __restrict__ outinv, float* __restrict__ ininv,
                           float* __restrict__ wself, int n) {
    int i = blockIdx.x * blockDim.x + threadIdx.x;
    if (i < n) {
        float oi = rsqrtf((float)(deg[i] + 1));       // +1 self-loop
        float ii = rsqrtf((float)(deg[n + i] + 1));
        outinv[i] = oi;
        ininv[i] = ii;
        wself[i] = oi * ii;
    }
}

// ---------------- exclusive scan over deg[0..n) -> offsets ----------------
__global__ __launch_bounds__(256) void scan_block_kernel(const int* __restrict__ in,
                                                         int* __restrict__ out,
                                                         int* __restrict__ blocksums, int n) {
    __shared__ int tmp[256];
    int tid = threadIdx.x;
    int gid = blockIdx.x * 256 + tid;
    int v = (gid < n) ? in[gid] : 0;
    tmp[tid] = v;
    __syncthreads();
    for (int off = 1; off < 256; off <<= 1) {
        int t = (tid >= off) ? tmp[tid - off] : 0;
        __syncthreads();
        tmp[tid] += t;
        __syncthreads();
    }
    if (gid < n) out[gid] = tmp[tid] - v;   // exclusive
    if (tid == 255) blocksums[blockIdx.x] = tmp[255];
}

__global__ __launch_bounds__(1024) void scan_sums_kernel(int* __restrict__ blocksums, int nb) {
    __shared__ int tmp[1024];
    int tid = threadIdx.x;
    int v = (tid < nb) ? blocksums[tid] : 0;
    tmp[tid] = v;
    __syncthreads();
    for (int off = 1; off < 1024; off <<= 1) {
        int t = (tid >= off) ? tmp[tid - off] : 0;
        __syncthreads();
        tmp[tid] += t;
        __syncthreads();
    }
    if (tid < nb) blocksums[tid] = tmp[tid] - v;  // exclusive block offsets
}

__global__ void add_offsets_kernel(int* __restrict__ out, const int* __restrict__ blocksums, int n) {
    int gid = blockIdx.x * 256 + threadIdx.x;
    if (gid < n) out[gid] += blocksums[blockIdx.x];
}

// ---------------- CSR scatter ----------------
// cursor starts as offsets; after this kernel cursor[i] == segment end.
// csr[0..E): row-CSR (neighbor=col, for s updates); csr[E..2E): col-CSR (neighbor=row, for t updates)
__global__ void build_csr_kernel(const int* __restrict__ row, const int* __restrict__ col,
                                 const float* __restrict__ outinv, const float* __restrict__ ininv,
                                 int* __restrict__ cursor, int2* __restrict__ csr, int E, int N) {
    int e = blockIdx.x * blockDim.x + threadIdx.x;
    if (e < E) {
        int r = row[e], c = col[e];
        float w = outinv[r] * ininv[c];
        int wb = __float_as_int(w);
        int pr = atomicAdd(&cursor[r], 1);
        csr[pr] = make_int2(c, wb);
        int pc = atomicAdd(&cursor[N + c], 1);
        csr[pc] = make_int2(r, wb);
    }
}

// ---------------- fused conv round: gather + self-loop + residual ----------------
// wave (64 lanes) per output node; lanes = feature dim.
// 8-deep software pipeline: 8 independent gathers in flight per wave (was 1 ->
// latency-bound at 2.2 TB/s / 27% HBM). Tail handled by predication (clamped
// index re-reads a cached row, weight forced to 0). CSR stream is nontemporal
// so the 16x-reused feature rows stay in L2.
__global__ __launch_bounds__(256) void conv_gather_kernel(
    const int* __restrict__ cursor, const int* __restrict__ deg,
    const int2* __restrict__ csr, const float* __restrict__ wself,
    const float* __restrict__ s_old, const float* __restrict__ t_old,
    float* __restrict__ s_new, float* __restrict__ t_new,
    const float* __restrict__ conv_w, int k, int N)
{
    int wid = (int)((blockIdx.x * blockDim.x + threadIdx.x) >> 6);
    int lane = threadIdx.x & 63;
    if (wid >= 2 * N) return;
    int side = (wid >= N) ? 1 : 0;
    int n = side ? wid - N : wid;
    const float* other = side ? s_old : t_old;
    const float* self  = side ? t_old : s_old;
    float* out         = side ? t_new : s_new;
    float coef = conv_w[2 * k + side];

    int end = cursor[wid];
    int d   = deg[wid];
    end = __builtin_amdgcn_readfirstlane(end);
    d   = __builtin_amdgcn_readfirstlane(d);
    int start = end - d;

    const unsigned long long* csr8 = (const unsigned long long*)csr;

    float acc[8];
    acc[0] = wself[n] * other[(size_t)n * 64 + lane];
    #pragma unroll
    for (int u = 1; u < 8; ++u) acc[u] = 0.f;

    for (int p = start; p < end; p += 8) {
        unsigned long long e[8];
        #pragma unroll
        for (int u = 0; u < 8; ++u) {
            int q = p + u;
            q = (q < end) ? q : (end - 1);        // clamp: harmless cached re-read
            e[u] = __builtin_nontemporal_load(&csr8[q]);
        }
        #pragma unroll
        for (int u = 0; u < 8; ++u) {
            float f = other[(size_t)(unsigned int)e[u] * 64 + lane];
            float w = (p + u < end) ? __int_as_float((int)(e[u] >> 32)) : 0.f;
            acc[u] = fmaf(w, f, acc[u]);
        }
    }

    float s01 = acc[0] + acc[1];
    float s23 = acc[2] + acc[3];
    float s45 = acc[4] + acc[5];
    float s67 = acc[6] + acc[7];
    float total = (s01 + s23) + (s45 + s67);

    size_t off = (size_t)n * 64 + lane;
    out[off] = fmaf(coef, total, self[off]);
}

extern "C" void kernel_launch(void* const* d_in, const int* in_sizes, int n_in,
                              void* d_out, int out_size, void* d_ws, size_t ws_size,
                              hipStream_t stream) {
    const int N = N_NODES;
    const int E = N_EDGES;

    const float* s_in  = (const float*)d_in[0];
    const float* t_in  = (const float*)d_in[1];
    const int*   ei    = (const int*)d_in[2];
    const int*   row   = ei;
    const int*   col   = ei + E;
    const float* Ws0 = (const float*)d_in[3];
    const float* bs0 = (const float*)d_in[4];
    const float* Wt0 = (const float*)d_in[5];
    const float* bt0 = (const float*)d_in[6];
    const float* Ws1 = (const float*)d_in[7];
    const float* bs1 = (const float*)d_in[8];
    const float* Wt1 = (const float*)d_in[9];
    const float* bt1 = (const float*)d_in[10];
    const float* Ws2 = (const float*)d_in[11];
    const float* bs2 = (const float*)d_in[12];
    const float* Wt2 = (const float*)d_in[13];
    const float* bt2 = (const float*)d_in[14];
    const float* conv_w = (const float*)d_in[15];

    float* out_s = (float*)d_out;
    float* out_t = (float*)d_out + (size_t)N * DIM_OUT;

    // workspace layout (4-byte units)
    float* ws = (float*)d_ws;
    float* H1 = ws;                                   // N*128 (later S1/T1)
    float* H2 = ws + (size_t)N * DIM_HID;             // N*128
    float* S0 = ws + 2 * (size_t)N * DIM_HID;         // N*64
    float* T0 = S0 + (size_t)N * DIM_OUT;             // N*64
    float* S1 = H1;                                   // alias (free after MLPs)
    float* T1 = H1 + (size_t)N * DIM_OUT;
    int2*  CSR    = (int2*)(T0 + (size_t)N * DIM_OUT);   // 2E int2
    float* OUTINV = (float*)(CSR + 2 * (size_t)E);       // N
    float* ININV  = OUTINV + N;                          // N
    float* WSELF  = ININV + N;                           // N
    int*   DEG    = (int*)(WSELF + N);                   // 2N
    int*   CURSOR = DEG + 2 * N;                         // 2N
    int*   BSUMS  = CURSOR + 2 * N;                      // ~1024

    const int twoN = 2 * N;
    const int scan_blocks = (twoN + 255) / 256;          // 782 <= 1024

    // ---- degrees ----
    zero_int_kernel<<<(twoN + 255) / 256, 256, 0, stream>>>(DEG, twoN);
    degree_kernel<<<(E + 255) / 256, 256, 0, stream>>>(row, col, DEG, E, N);
    inv_kernel<<<(N + 255) / 256, 256, 0, stream>>>(DEG, OUTINV, ININV, WSELF, N);

    // ---- exclusive scan of DEG -> CURSOR (offsets) ----
    scan_block_kernel<<<scan_blocks, 256, 0, stream>>>(DEG, CURSOR, BSUMS, twoN);
    scan_sums_kernel<<<1, 1024, 0, stream>>>(BSUMS, scan_blocks);
    add_offsets_kernel<<<scan_blocks, 256, 0, stream>>>(CURSOR, BSUMS, twoN);

    // ---- CSR scatter (cursor -> ends) ----
    build_csr_kernel<<<(E + 255) / 256, 256, 0, stream>>>(row, col, OUTINV, ININV, CURSOR, CSR, E, N);

    // ---- MLPs ----
    dim3 blk(256);
    dim3 g1((N + BM - 1) / BM, DIM_HID / BN);
    dim3 g3((N + BM - 1) / BM, DIM_OUT / BN);
    gemm_bias_act<<<g1, blk, 0, stream>>>(s_in, Ws0, bs0, H2, N, DIM_IN,  DIM_HID, 1);
    gemm_bias_act<<<g1, blk, 0, stream>>>(H2,  Ws1, bs1, H1, N, DIM_HID, DIM_HID, 1);
    gemm_bias_act<<<g3, blk, 0, stream>>>(H1,  Ws2, bs2, S0, N, DIM_HID, DIM_OUT, 0);
    gemm_bias_act<<<g1, blk, 0, stream>>>(t_in, Wt0, bt0, H2, N, DIM_IN,  DIM_HID, 1);
    gemm_bias_act<<<g1, blk, 0, stream>>>(H2,  Wt1, bt1, H1, N, DIM_HID, DIM_HID, 1);
    gemm_bias_act<<<g3, blk, 0, stream>>>(H1,  Wt2, bt2, T0, N, DIM_HID, DIM_OUT, 0);

    // ---- 3 conv rounds, wave-per-node gather ----
    const int gather_blocks = (twoN * 64 + 255) / 256;   // 4 waves/block
    conv_gather_kernel<<<gather_blocks, 256, 0, stream>>>(CURSOR, DEG, CSR, WSELF, S0, T0, S1, T1, conv_w, 0, N);
    conv_gather_kernel<<<gather_blocks, 256, 0, stream>>>(CURSOR, DEG, CSR, WSELF, S1, T1, S0, T0, conv_w, 1, N);
    conv_gather_kernel<<<gather_blocks, 256, 0, stream>>>(CURSOR, DEG, CSR, WSELF, S0, T0, out_s, out_t, conv_w, 2, N);
}

// Round 2
// 1143.047 us; speedup vs baseline: 1.4346x; 1.1008x over previous
//
#include <hip/hip_runtime.h>

#define N_NODES 100000
#define N_EDGES 1600000
#define DIM_IN  256
#define DIM_HID 128
#define DIM_OUT 64

// ---------------- GEMM: C = act(A @ W + bias) ----------------
// 128x64 tile, BK=32, 256 threads, 8x4 acc/thread.
// A-tile stored transposed [BK][BM] with XOR swizzle m ^ ((kk>>2)<<3):
//   staging writes (stride-512B) and compute reads are both <=2-way bank aliased.
#define BM 128
#define BN 64
#define BK 32

__global__ __launch_bounds__(256, 4) void gemm_bias_act(
    const float* __restrict__ A, const float* __restrict__ W,
    const float* __restrict__ bias, float* __restrict__ C,
    int M, int K, int F, int do_relu)
{
    __shared__ float As[BK][BM];   // swizzled
    __shared__ float Ws[BK][BN];
    const int tid = threadIdx.x;
    const int tx = tid & 15;        // n: 4 cols each
    const int ty = tid >> 4;        // m: 8 rows each
    const int bm = blockIdx.x * BM;
    const int bn = blockIdx.y * BN;

    const int am  = tid >> 3;       // A staging: row 0..31 (+32*it)
    const int akq = tid & 7;        // A staging: float4 index within 32-k row
    const int wr  = tid >> 4;       // W staging: row 0..15 (+16*it)
    const int wcq = tid & 15;       // W staging: float4 col

    float acc[8][4] = {};

    for (int k0 = 0; k0 < K; k0 += BK) {
        // stage A tile (128 rows x 32 k), transposed + swizzled
        #pragma unroll
        for (int it = 0; it < 4; ++it) {
            int m = am + it * 32;
            int gm = bm + m;
            float4 a4 = make_float4(0.f, 0.f, 0.f, 0.f);
            if (gm < M)
                a4 = *(const float4*)&A[(size_t)gm * K + k0 + akq * 4];
            int msw = m ^ (akq << 3);          // akq == kk>>2 for kk in [akq*4, akq*4+3]
            As[akq * 4 + 0][msw] = a4.x;
            As[akq * 4 + 1][msw] = a4.y;
            As[akq * 4 + 2][msw] = a4.z;
            As[akq * 4 + 3][msw] = a4.w;
        }
        // stage W tile (32 x 64)
        #pragma unroll
        for (int it = 0; it < 2; ++it) {
            int r = wr + it * 16;
            float4 w4 = *(const float4*)&W[(size_t)(k0 + r) * F + bn + wcq * 4];
            *(float4*)&Ws[r][wcq * 4] = w4;
        }
        __syncthreads();
        #pragma unroll
        for (int kk = 0; kk < BK; ++kk) {
            const float* ap = &As[kk][(ty * 8) ^ (((kk >> 2) & 7) << 3)];
            float4 a0 = *(const float4*)(ap);
            float4 a1 = *(const float4*)(ap + 4);
            float4 w4 = *(const float4*)&Ws[kk][tx * 4];
            float a[8] = {a0.x, a0.y, a0.z, a0.w, a1.x, a1.y, a1.z, a1.w};
            float w[4] = {w4.x, w4.y, w4.z, w4.w};
            #pragma unroll
            for (int i = 0; i < 8; ++i)
                #pragma unroll
                for (int j = 0; j < 4; ++j)
                    acc[i][j] = fmaf(a[i], w[j], acc[i][j]);
        }
        __syncthreads();
    }
    float4 b4 = *(const float4*)&bias[bn + tx * 4];
    #pragma unroll
    for (int i = 0; i < 8; ++i) {
        int m = bm + ty * 8 + i;
        if (m < M) {
            float4 v;
            v.x = acc[i][0] + b4.x;
            v.y = acc[i][1] + b4.y;
            v.z = acc[i][2] + b4.z;
            v.w = acc[i][3] + b4.w;
            if (do_relu) {
                v.x = fmaxf(v.x, 0.f); v.y = fmaxf(v.y, 0.f);
                v.z = fmaxf(v.z, 0.f); v.w = fmaxf(v.w, 0.f);
            }
            *(float4*)&C[(size_t)m * F + bn + tx * 4] = v;
        }
    }
}

// ---------------- degree + rank ----------------
__global__ void zero_int_kernel(int* __restrict__ p, int n) {
    int i = blockIdx.x * blockDim.x + threadIdx.x;
    if (i < n) p[i] = 0;
}

// deg layout: [0,N) = outdeg (row), [N,2N) = indeg (col)
// The atomicAdd return IS the edge's rank within its node segment -> persist it
// (coalesced) so the CSR scatter needs no atomics at all.
__global__ void degree_rank_kernel(const int* __restrict__ row, const int* __restrict__ col,
                                   int* __restrict__ deg,
                                   int* __restrict__ rank_r, int* __restrict__ rank_c,
                                   int E, int N) {
    int e = blockIdx.x * blockDim.x + threadIdx.x;
    if (e < E) {
        rank_r[e] = atomicAdd(&deg[row[e]], 1);
        rank_c[e] = atomicAdd(&deg[N + col[e]], 1);
    }
}

__global__ void inv_kernel(const int* __restrict__ deg,
                           float* __restrict__ outinv, float* __restrict__ ininv,
                           float* __restrict__ wself, int n) {
    int i = blockIdx.x * blockDim.x + threadIdx.x;
    if (i < n) {
        float oi = rsqrtf((float)(deg[i] + 1));       // +1 self-loop
        float ii = rsqrtf((float)(deg[n + i] + 1));
        outinv[i] = oi;
        ininv[i] = ii;
        wself[i] = oi * ii;
    }
}

// ---------------- exclusive scan over deg[0..n) -> offsets ----------------
__global__ __launch_bounds__(256) void scan_block_kernel(const int* __restrict__ in,
                                                         int* __restrict__ out,
                                                         int* __restrict__ blocksums, int n) {
    __shared__ int tmp[256];
    int tid = threadIdx.x;
    int gid = blockIdx.x * 256 + tid;
    int v = (gid < n) ? in[gid] : 0;
    tmp[tid] = v;
    __syncthreads();
    for (int off = 1; off < 256; off <<= 1) {
        int t = (tid >= off) ? tmp[tid - off] : 0;
        __syncthreads();
        tmp[tid] += t;
        __syncthreads();
    }
    if (gid < n) out[gid] = tmp[tid] - v;   // exclusive
    if (tid == 255) blocksums[blockIdx.x] = tmp[255];
}

__global__ __launch_bounds__(1024) void scan_sums_kernel(int* __restrict__ blocksums, int nb) {
    __shared__ int tmp[1024];
    int tid = threadIdx.x;
    int v = (tid < nb) ? blocksums[tid] : 0;
    tmp[tid] = v;
    __syncthreads();
    for (int off = 1; off < 1024; off <<= 1) {
        int t = (tid >= off) ? tmp[tid - off] : 0;
        __syncthreads();
        tmp[tid] += t;
        __syncthreads();
    }
    if (tid < nb) blocksums[tid] = tmp[tid] - v;  // exclusive block offsets
}

__global__ void add_offsets_kernel(int* __restrict__ out, const int* __restrict__ blocksums, int n) {
    int gid = blockIdx.x * 256 + threadIdx.x;
    if (gid < n) out[gid] += blocksums[blockIdx.x];
}

// ---------------- CSR scatter (atomic-free) ----------------
// offs[] = segment starts (exclusive scan of deg); position = offs[node] + rank.
// Pure fire-and-forget scatter: no long-latency dependence in front of the stores.
// csr[0..E): row-CSR (neighbor=col, for s updates); csr[E..2E): col-CSR (neighbor=row)
__global__ void build_csr_kernel(const int* __restrict__ row, const int* __restrict__ col,
                                 const int* __restrict__ rank_r, const int* __restrict__ rank_c,
                                 const float* __restrict__ outinv, const float* __restrict__ ininv,
                                 const int* __restrict__ offs, int2* __restrict__ csr, int E, int N) {
    int e = blockIdx.x * blockDim.x + threadIdx.x;
    if (e < E) {
        int r = row[e], c = col[e];
        float w = outinv[r] * ininv[c];
        int wb = __float_as_int(w);
        csr[offs[r] + rank_r[e]]     = make_int2(c, wb);
        csr[offs[N + c] + rank_c[e]] = make_int2(r, wb);
    }
}

// ---------------- fused conv round: gather + self-loop + residual ----------------
// wave (64 lanes) per output node; lanes = feature dim.
// 8-deep software pipeline keeps 8 independent gathers in flight per wave.
// offs[] = segment starts; end = start + deg.
__global__ __launch_bounds__(256) void conv_gather_kernel(
    const int* __restrict__ offs, const int* __restrict__ deg,
    const int2* __restrict__ csr, const float* __restrict__ wself,
    const float* __restrict__ s_old, const float* __restrict__ t_old,
    float* __restrict__ s_new, float* __restrict__ t_new,
    const float* __restrict__ conv_w, int k, int N)
{
    int wid = (int)((blockIdx.x * blockDim.x + threadIdx.x) >> 6);
    int lane = threadIdx.x & 63;
    if (wid >= 2 * N) return;
    int side = (wid >= N) ? 1 : 0;
    int n = side ? wid - N : wid;
    const float* other = side ? s_old : t_old;
    const float* self  = side ? t_old : s_old;
    float* out         = side ? t_new : s_new;
    float coef = conv_w[2 * k + side];

    int start = offs[wid];
    int d     = deg[wid];
    start = __builtin_amdgcn_readfirstlane(start);
    d     = __builtin_amdgcn_readfirstlane(d);
    int end = start + d;

    const unsigned long long* csr8 = (const unsigned long long*)csr;

    float acc[8];
    acc[0] = wself[n] * other[(size_t)n * 64 + lane];
    #pragma unroll
    for (int u = 1; u < 8; ++u) acc[u] = 0.f;

    for (int p = start; p < end; p += 8) {
        unsigned long long e[8];
        #pragma unroll
        for (int u = 0; u < 8; ++u) {
            int q = p + u;
            q = (q < end) ? q : (end - 1);        // clamp: harmless cached re-read
            e[u] = __builtin_nontemporal_load(&csr8[q]);
        }
        #pragma unroll
        for (int u = 0; u < 8; ++u) {
            float f = other[(size_t)(unsigned int)e[u] * 64 + lane];
            float w = (p + u < end) ? __int_as_float((int)(e[u] >> 32)) : 0.f;
            acc[u] = fmaf(w, f, acc[u]);
        }
    }

    float s01 = acc[0] + acc[1];
    float s23 = acc[2] + acc[3];
    float s45 = acc[4] + acc[5];
    float s67 = acc[6] + acc[7];
    float total = (s01 + s23) + (s45 + s67);

    size_t off = (size_t)n * 64 + lane;
    out[off] = fmaf(coef, total, self[off]);
}

extern "C" void kernel_launch(void* const* d_in, const int* in_sizes, int n_in,
                              void* d_out, int out_size, void* d_ws, size_t ws_size,
                              hipStream_t stream) {
    const int N = N_NODES;
    const int E = N_EDGES;

    const float* s_in  = (const float*)d_in[0];
    const float* t_in  = (const float*)d_in[1];
    const int*   ei    = (const int*)d_in[2];
    const int*   row   = ei;
    const int*   col   = ei + E;
    const float* Ws0 = (const float*)d_in[3];
    const float* bs0 = (const float*)d_in[4];
    const float* Wt0 = (const float*)d_in[5];
    const float* bt0 = (const float*)d_in[6];
    const float* Ws1 = (const float*)d_in[7];
    const float* bs1 = (const float*)d_in[8];
    const float* Wt1 = (const float*)d_in[9];
    const float* bt1 = (const float*)d_in[10];
    const float* Ws2 = (const float*)d_in[11];
    const float* bs2 = (const float*)d_in[12];
    const float* Wt2 = (const float*)d_in[13];
    const float* bt2 = (const float*)d_in[14];
    const float* conv_w = (const float*)d_in[15];

    float* out_s = (float*)d_out;
    float* out_t = (float*)d_out + (size_t)N * DIM_OUT;

    // workspace layout (4-byte units)
    float* ws = (float*)d_ws;
    float* H1 = ws;                                   // N*128 (later S1/T1)
    float* H2 = ws + (size_t)N * DIM_HID;             // N*128
    float* S0 = ws + 2 * (size_t)N * DIM_HID;         // N*64
    float* T0 = S0 + (size_t)N * DIM_OUT;             // N*64
    float* S1 = H1;                                   // alias (free after MLPs)
    float* T1 = H1 + (size_t)N * DIM_OUT;
    int2*  CSR    = (int2*)(T0 + (size_t)N * DIM_OUT);   // 2E int2
    float* OUTINV = (float*)(CSR + 2 * (size_t)E);       // N
    float* ININV  = OUTINV + N;                          // N
    float* WSELF  = ININV + N;                           // N
    int*   DEG    = (int*)(WSELF + N);                   // 2N
    int*   OFFS   = DEG + 2 * N;                         // 2N (segment starts)
    int*   BSUMS  = OFFS + 2 * N;                        // ~1024
    // RANK arrays alias H1: produced by degree_rank, consumed by build_csr,
    // both of which run before any GEMM touches H1/H2.
    int*   RANKR  = (int*)H1;                            // E
    int*   RANKC  = RANKR + E;                           // E

    const int twoN = 2 * N;
    const int scan_blocks = (twoN + 255) / 256;          // 782 <= 1024

    // ---- degrees + per-edge ranks ----
    zero_int_kernel<<<(twoN + 255) / 256, 256, 0, stream>>>(DEG, twoN);
    degree_rank_kernel<<<(E + 255) / 256, 256, 0, stream>>>(row, col, DEG, RANKR, RANKC, E, N);
    inv_kernel<<<(N + 255) / 256, 256, 0, stream>>>(DEG, OUTINV, ININV, WSELF, N);

    // ---- exclusive scan of DEG -> OFFS (segment starts) ----
    scan_block_kernel<<<scan_blocks, 256, 0, stream>>>(DEG, OFFS, BSUMS, twoN);
    scan_sums_kernel<<<1, 1024, 0, stream>>>(BSUMS, scan_blocks);
    add_offsets_kernel<<<scan_blocks, 256, 0, stream>>>(OFFS, BSUMS, twoN);

    // ---- CSR scatter (atomic-free) ----
    build_csr_kernel<<<(E + 255) / 256, 256, 0, stream>>>(row, col, RANKR, RANKC,
                                                          OUTINV, ININV, OFFS, CSR, E, N);

    // ---- MLPs ----
    dim3 blk(256);
    dim3 g1((N + BM - 1) / BM, DIM_HID / BN);
    dim3 g3((N + BM - 1) / BM, DIM_OUT / BN);
    gemm_bias_act<<<g1, blk, 0, stream>>>(s_in, Ws0, bs0, H2, N, DIM_IN,  DIM_HID, 1);
    gemm_bias_act<<<g1, blk, 0, stream>>>(H2,  Ws1, bs1, H1, N, DIM_HID, DIM_HID, 1);
    gemm_bias_act<<<g3, blk, 0, stream>>>(H1,  Ws2, bs2, S0, N, DIM_HID, DIM_OUT, 0);
    gemm_bias_act<<<g1, blk, 0, stream>>>(t_in, Wt0, bt0, H2, N, DIM_IN,  DIM_HID, 1);
    gemm_bias_act<<<g1, blk, 0, stream>>>(H2,  Wt1, bt1, H1, N, DIM_HID, DIM_HID, 1);
    gemm_bias_act<<<g3, blk, 0, stream>>>(H1,  Wt2, bt2, T0, N, DIM_HID, DIM_OUT, 0);

    // ---- 3 conv rounds, wave-per-node gather ----
    const int gather_blocks = (twoN * 64 + 255) / 256;   // 4 waves/block
    conv_gather_kernel<<<gather_blocks, 256, 0, stream>>>(OFFS, DEG, CSR, WSELF, S0, T0, S1, T1, conv_w, 0, N);
    conv_gather_kernel<<<gather_blocks, 256, 0, stream>>>(OFFS, DEG, CSR, WSELF, S1, T1, S0, T0, conv_w, 1, N);
    conv_gather_kernel<<<gather_blocks, 256, 0, stream>>>(OFFS, DEG, CSR, WSELF, S0, T0, out_s, out_t, conv_w, 2, N);
}

// Round 3
// 1065.233 us; speedup vs baseline: 1.5394x; 1.0730x over previous
//
#include <hip/hip_runtime.h>

#define N_NODES 100000
#define N_EDGES 1600000
#define DIM_IN  256
#define DIM_HID 128
#define DIM_OUT 64

// ---------------- GEMM tile: C = act(A @ W + bias) ----------------
// 128x64 tile, BK=32, 256 threads, 8x4 acc/thread.
// A-tile stored transposed [BK][BM] with XOR swizzle m ^ ((kk>>2)<<3).
#define BM 128
#define BN 64
#define BK 32
#define GXM ((N_NODES + BM - 1) / BM)   // 782 M-tiles

__device__ __forceinline__ void gemm_tile(
    int bx, int by,
    const float* __restrict__ A, const float* __restrict__ W,
    const float* __restrict__ bias, float* __restrict__ C,
    int M, int K, int F, int do_relu,
    float (*As)[BM], float (*Ws)[BN])
{
    const int tid = threadIdx.x;
    const int tx = tid & 15;        // n: 4 cols each
    const int ty = tid >> 4;        // m: 8 rows each
    const int bm = bx * BM;
    const int bn = by * BN;

    const int am  = tid >> 3;       // A staging: row 0..31 (+32*it)
    const int akq = tid & 7;        // A staging: float4 index within 32-k row
    const int wr  = tid >> 4;       // W staging: row 0..15 (+16*it)
    const int wcq = tid & 15;       // W staging: float4 col

    float acc[8][4] = {};

    for (int k0 = 0; k0 < K; k0 += BK) {
        #pragma unroll
        for (int it = 0; it < 4; ++it) {
            int m = am + it * 32;
            int gm = bm + m;
            float4 a4 = make_float4(0.f, 0.f, 0.f, 0.f);
            if (gm < M)
                a4 = *(const float4*)&A[(size_t)gm * K + k0 + akq * 4];
            int msw = m ^ (akq << 3);
            As[akq * 4 + 0][msw] = a4.x;
            As[akq * 4 + 1][msw] = a4.y;
            As[akq * 4 + 2][msw] = a4.z;
            As[akq * 4 + 3][msw] = a4.w;
        }
        #pragma unroll
        for (int it = 0; it < 2; ++it) {
            int r = wr + it * 16;
            float4 w4 = *(const float4*)&W[(size_t)(k0 + r) * F + bn + wcq * 4];
            *(float4*)&Ws[r][wcq * 4] = w4;
        }
        __syncthreads();
        #pragma unroll
        for (int kk = 0; kk < BK; ++kk) {
            const float* ap = &As[kk][(ty * 8) ^ (((kk >> 2) & 7) << 3)];
            float4 a0 = *(const float4*)(ap);
            float4 a1 = *(const float4*)(ap + 4);
            float4 w4 = *(const float4*)&Ws[kk][tx * 4];
            float a[8] = {a0.x, a0.y, a0.z, a0.w, a1.x, a1.y, a1.z, a1.w};
            float w[4] = {w4.x, w4.y, w4.z, w4.w};
            #pragma unroll
            for (int i = 0; i < 8; ++i)
                #pragma unroll
                for (int j = 0; j < 4; ++j)
                    acc[i][j] = fmaf(a[i], w[j], acc[i][j]);
        }
        __syncthreads();
    }
    float4 b4 = *(const float4*)&bias[bn + tx * 4];
    #pragma unroll
    for (int i = 0; i < 8; ++i) {
        int m = bm + ty * 8 + i;
        if (m < M) {
            float4 v;
            v.x = acc[i][0] + b4.x;
            v.y = acc[i][1] + b4.y;
            v.z = acc[i][2] + b4.z;
            v.w = acc[i][3] + b4.w;
            if (do_relu) {
                v.x = fmaxf(v.x, 0.f); v.y = fmaxf(v.y, 0.f);
                v.z = fmaxf(v.z, 0.f); v.w = fmaxf(v.w, 0.f);
            }
            *(float4*)&C[(size_t)m * F + bn + tx * 4] = v;
        }
    }
}

__global__ __launch_bounds__(256, 4) void gemm_bias_act(
    const float* __restrict__ A, const float* __restrict__ W,
    const float* __restrict__ bias, float* __restrict__ C,
    int M, int K, int F, int do_relu)
{
    __shared__ float As[BK][BM];
    __shared__ float Ws[BK][BN];
    gemm_tile(blockIdx.x, blockIdx.y, A, W, bias, C, M, K, F, do_relu, As, Ws);
}

// ---------------- fused A: degree+rank (coherence-bound) || GEMM-L0-s (VALU-bound) ----
// block mapping interleaves 1 gemm : 4 degree so both cohorts are co-resident.
// deg layout: [0,N) = outdeg (row), [N,2N) = indeg (col)
__global__ __launch_bounds__(256, 4) void fusedA_kernel(
    const float* __restrict__ A, const float* __restrict__ W,
    const float* __restrict__ bias, float* __restrict__ C,
    int M, int K, int F,
    const int* __restrict__ row, const int* __restrict__ col,
    int* __restrict__ deg, int* __restrict__ rank_r, int* __restrict__ rank_c,
    int E, int N, int deg_blocks)
{
    __shared__ float As[BK][BM];
    __shared__ float Ws[BK][BN];
    int g = blockIdx.x / 5;
    int r = blockIdx.x % 5;
    if (r == 0) {
        gemm_tile(g % GXM, g / GXM, A, W, bias, C, M, K, F, 1, As, Ws);
    } else {
        int db = g * 4 + (r - 1);
        if (db < deg_blocks) {
            int e = db * 256 + threadIdx.x;
            if (e < E) {
                rank_r[e] = atomicAdd(&deg[row[e]], 1);
                rank_c[e] = atomicAdd(&deg[N + col[e]], 1);
            }
        }
    }
}

// ---------------- fused B: CSR scatter (fire-and-forget) || GEMM-L1-s ----------------
// position = offs[node] + rank (precomputed) -> no atomics.
// csr[0..E): row-CSR (neighbor=col); csr[E..2E): col-CSR (neighbor=row)
__global__ __launch_bounds__(256, 4) void fusedB_kernel(
    const float* __restrict__ A, const float* __restrict__ W,
    const float* __restrict__ bias, float* __restrict__ C,
    int M, int K, int F,
    const int* __restrict__ row, const int* __restrict__ col,
    const int* __restrict__ rank_r, const int* __restrict__ rank_c,
    const float* __restrict__ outinv, const float* __restrict__ ininv,
    const int* __restrict__ offs, int2* __restrict__ csr,
    int E, int N, int csr_blocks)
{
    __shared__ float As[BK][BM];
    __shared__ float Ws[BK][BN];
    int g = blockIdx.x / 5;
    int r = blockIdx.x % 5;
    if (r == 0) {
        gemm_tile(g % GXM, g / GXM, A, W, bias, C, M, K, F, 1, As, Ws);
    } else {
        int db = g * 4 + (r - 1);
        if (db < csr_blocks) {
            int e = db * 256 + threadIdx.x;
            if (e < E) {
                int rr = row[e], cc = col[e];
                float w = outinv[rr] * ininv[cc];
                int wb = __float_as_int(w);
                csr[offs[rr] + rank_r[e]]     = make_int2(cc, wb);
                csr[offs[N + cc] + rank_c[e]] = make_int2(rr, wb);
            }
        }
    }
}

// ---------------- degree helpers ----------------
__global__ void zero_int_kernel(int* __restrict__ p, int n) {
    int i = blockIdx.x * blockDim.x + threadIdx.x;
    if (i < n) p[i] = 0;
}

// ---------------- scan (blocks 0..sb-1) fused with inv (blocks sb..) ----------------
__global__ __launch_bounds__(256) void scan_inv_kernel(
    const int* __restrict__ in, int* __restrict__ out,
    int* __restrict__ blocksums, int n2,          // scan over n2 = 2N
    float* __restrict__ outinv, float* __restrict__ ininv,
    float* __restrict__ wself, int n, int scan_blocks)
{
    int tid = threadIdx.x;
    if ((int)blockIdx.x < scan_blocks) {
        __shared__ int tmp[256];
        int gid = blockIdx.x * 256 + tid;
        int v = (gid < n2) ? in[gid] : 0;
        tmp[tid] = v;
        __syncthreads();
        for (int off = 1; off < 256; off <<= 1) {
            int t = (tid >= off) ? tmp[tid - off] : 0;
            __syncthreads();
            tmp[tid] += t;
            __syncthreads();
        }
        if (gid < n2) out[gid] = tmp[tid] - v;   // exclusive
        if (tid == 255) blocksums[blockIdx.x] = tmp[255];
    } else {
        int i = ((int)blockIdx.x - scan_blocks) * 256 + tid;
        if (i < n) {
            float oi = rsqrtf((float)(in[i] + 1));       // +1 self-loop
            float ii = rsqrtf((float)(in[n + i] + 1));
            outinv[i] = oi;
            ininv[i] = ii;
            wself[i] = oi * ii;
        }
    }
}

__global__ __launch_bounds__(1024) void scan_sums_kernel(int* __restrict__ blocksums, int nb) {
    __shared__ int tmp[1024];
    int tid = threadIdx.x;
    int v = (tid < nb) ? blocksums[tid] : 0;
    tmp[tid] = v;
    __syncthreads();
    for (int off = 1; off < 1024; off <<= 1) {
        int t = (tid >= off) ? tmp[tid - off] : 0;
        __syncthreads();
        tmp[tid] += t;
        __syncthreads();
    }
    if (tid < nb) blocksums[tid] = tmp[tid] - v;  // exclusive block offsets
}

__global__ void add_offsets_kernel(int* __restrict__ out, const int* __restrict__ blocksums, int n) {
    int gid = blockIdx.x * 256 + threadIdx.x;
    if (gid < n) out[gid] += blocksums[blockIdx.x];
}

// ---------------- fused conv round: gather + self-loop + residual ----------------
// wave (64 lanes) per output node; lanes = feature dim.
// 8-deep software pipeline keeps 8 independent gathers in flight per wave.
__global__ __launch_bounds__(256) void conv_gather_kernel(
    const int* __restrict__ offs, const int* __restrict__ deg,
    const int2* __restrict__ csr, const float* __restrict__ wself,
    const float* __restrict__ s_old, const float* __restrict__ t_old,
    float* __restrict__ s_new, float* __restrict__ t_new,
    const float* __restrict__ conv_w, int k, int N)
{
    int wid = (int)((blockIdx.x * blockDim.x + threadIdx.x) >> 6);
    int lane = threadIdx.x & 63;
    if (wid >= 2 * N) return;
    int side = (wid >= N) ? 1 : 0;
    int n = side ? wid - N : wid;
    const float* other = side ? s_old : t_old;
    const float* self  = side ? t_old : s_old;
    float* out         = side ? t_new : s_new;
    float coef = conv_w[2 * k + side];

    int start = offs[wid];
    int d     = deg[wid];
    start = __builtin_amdgcn_readfirstlane(start);
    d     = __builtin_amdgcn_readfirstlane(d);
    int end = start + d;

    const unsigned long long* csr8 = (const unsigned long long*)csr;

    float acc[8];
    acc[0] = wself[n] * other[(size_t)n * 64 + lane];
    #pragma unroll
    for (int u = 1; u < 8; ++u) acc[u] = 0.f;

    for (int p = start; p < end; p += 8) {
        unsigned long long e[8];
        #pragma unroll
        for (int u = 0; u < 8; ++u) {
            int q = p + u;
            q = (q < end) ? q : (end - 1);        // clamp: harmless cached re-read
            e[u] = __builtin_nontemporal_load(&csr8[q]);
        }
        #pragma unroll
        for (int u = 0; u < 8; ++u) {
            float f = other[(size_t)(unsigned int)e[u] * 64 + lane];
            float w = (p + u < end) ? __int_as_float((int)(e[u] >> 32)) : 0.f;
            acc[u] = fmaf(w, f, acc[u]);
        }
    }

    float s01 = acc[0] + acc[1];
    float s23 = acc[2] + acc[3];
    float s45 = acc[4] + acc[5];
    float s67 = acc[6] + acc[7];
    float total = (s01 + s23) + (s45 + s67);

    size_t off = (size_t)n * 64 + lane;
    out[off] = fmaf(coef, total, self[off]);
}

extern "C" void kernel_launch(void* const* d_in, const int* in_sizes, int n_in,
                              void* d_out, int out_size, void* d_ws, size_t ws_size,
                              hipStream_t stream) {
    const int N = N_NODES;
    const int E = N_EDGES;

    const float* s_in  = (const float*)d_in[0];
    const float* t_in  = (const float*)d_in[1];
    const int*   ei    = (const int*)d_in[2];
    const int*   row   = ei;
    const int*   col   = ei + E;
    const float* Ws0 = (const float*)d_in[3];
    const float* bs0 = (const float*)d_in[4];
    const float* Wt0 = (const float*)d_in[5];
    const float* bt0 = (const float*)d_in[6];
    const float* Ws1 = (const float*)d_in[7];
    const float* bs1 = (const float*)d_in[8];
    const float* Wt1 = (const float*)d_in[9];
    const float* bt1 = (const float*)d_in[10];
    const float* Ws2 = (const float*)d_in[11];
    const float* bs2 = (const float*)d_in[12];
    const float* Wt2 = (const float*)d_in[13];
    const float* bt2 = (const float*)d_in[14];
    const float* conv_w = (const float*)d_in[15];

    float* out_s = (float*)d_out;
    float* out_t = (float*)d_out + (size_t)N * DIM_OUT;

    // workspace layout (4-byte units)
    float* ws = (float*)d_ws;
    float* H1 = ws;                                   // N*128 (later S1/T1)
    float* H2 = ws + (size_t)N * DIM_HID;             // N*128
    float* S0 = ws + 2 * (size_t)N * DIM_HID;         // N*64
    float* T0 = S0 + (size_t)N * DIM_OUT;             // N*64
    float* S1 = H1;                                   // alias (free after MLPs)
    float* T1 = H1 + (size_t)N * DIM_OUT;
    int2*  CSR    = (int2*)(T0 + (size_t)N * DIM_OUT);   // 2E int2
    float* OUTINV = (float*)(CSR + 2 * (size_t)E);       // N
    float* ININV  = OUTINV + N;                          // N
    float* WSELF  = ININV + N;                           // N
    int*   DEG    = (int*)(WSELF + N);                   // 2N
    int*   OFFS   = DEG + 2 * N;                         // 2N (segment starts)
    int*   BSUMS  = OFFS + 2 * N;                        // ~1024
    // RANK arrays alias S0/T0: produced in fusedA, consumed in fusedB, both of
    // which complete strictly before GEMM-L2-s writes S0. (Cannot alias H1:
    // fusedB's GEMM writes H1 concurrently with the CSR blocks reading RANK.)
    int*   RANKR  = (int*)S0;                            // E
    int*   RANKC  = RANKR + E;                           // E

    const int twoN = 2 * N;
    const int scan_blocks = (twoN + 255) / 256;          // 782
    const int inv_blocks  = (N + 255) / 256;             // 391
    const int edge_blocks = (E + 255) / 256;             // 6250
    const int gemm_blocks = GXM * (DIM_HID / BN);        // 782*2 = 1564
    const int fused_blocks = gemm_blocks * 5;            // 1:4 interleave

    // ---- zero degree counters ----
    zero_int_kernel<<<(twoN + 255) / 256, 256, 0, stream>>>(DEG, twoN);

    // ---- fusedA: degree+rank || GEMM-L0-s ----
    fusedA_kernel<<<fused_blocks, 256, 0, stream>>>(
        s_in, Ws0, bs0, H2, N, DIM_IN, DIM_HID,
        row, col, DEG, RANKR, RANKC, E, N, edge_blocks);

    // ---- scan of DEG -> OFFS (block-local) fused with inv ----
    scan_inv_kernel<<<scan_blocks + inv_blocks, 256, 0, stream>>>(
        DEG, OFFS, BSUMS, twoN, OUTINV, ININV, WSELF, N, scan_blocks);
    scan_sums_kernel<<<1, 1024, 0, stream>>>(BSUMS, scan_blocks);
    add_offsets_kernel<<<scan_blocks, 256, 0, stream>>>(OFFS, BSUMS, twoN);

    // ---- fusedB: CSR scatter || GEMM-L1-s ----
    fusedB_kernel<<<fused_blocks, 256, 0, stream>>>(
        H2, Ws1, bs1, H1, N, DIM_HID, DIM_HID,
        row, col, RANKR, RANKC, OUTINV, ININV, OFFS, CSR, E, N, edge_blocks);

    // ---- remaining MLPs ----
    dim3 blk(256);
    dim3 g1(GXM, DIM_HID / BN);
    dim3 g3(GXM, DIM_OUT / BN);
    gemm_bias_act<<<g3, blk, 0, stream>>>(H1,  Ws2, bs2, S0, N, DIM_HID, DIM_OUT, 0);
    gemm_bias_act<<<g1, blk, 0, stream>>>(t_in, Wt0, bt0, H2, N, DIM_IN,  DIM_HID, 1);
    gemm_bias_act<<<g1, blk, 0, stream>>>(H2,  Wt1, bt1, H1, N, DIM_HID, DIM_HID, 1);
    gemm_bias_act<<<g3, blk, 0, stream>>>(H1,  Wt2, bt2, T0, N, DIM_HID, DIM_OUT, 0);

    // ---- 3 conv rounds, wave-per-node gather ----
    const int gather_blocks = (twoN * 64 + 255) / 256;   // 4 waves/block
    conv_gather_kernel<<<gather_blocks, 256, 0, stream>>>(OFFS, DEG, CSR, WSELF, S0, T0, S1, T1, conv_w, 0, N);
    conv_gather_kernel<<<gather_blocks, 256, 0, stream>>>(OFFS, DEG, CSR, WSELF, S1, T1, S0, T0, conv_w, 1, N);
    conv_gather_kernel<<<gather_blocks, 256, 0, stream>>>(OFFS, DEG, CSR, WSELF, S0, T0, out_s, out_t, conv_w, 2, N);
}

// Round 4
// 1059.146 us; speedup vs baseline: 1.5482x; 1.0057x over previous
//
#include <hip/hip_runtime.h>

#define N_NODES 100000
#define N_EDGES 1600000
#define DIM_IN  256
#define DIM_HID 128
#define DIM_OUT 64

// ---------------- GEMM tile: C = act(A @ W + bias) ----------------
// 128x64 tile, BK=32, 256 threads, 8x4 acc/thread.
// A-tile stored transposed [BK][BM] with XOR swizzle m ^ ((kk>>2)<<3).
#define BM 128
#define BN 64
#define BK 32
#define GXM ((N_NODES + BM - 1) / BM)   // 782 M-tiles

__device__ __forceinline__ void gemm_tile(
    int bx, int by,
    const float* __restrict__ A, const float* __restrict__ W,
    const float* __restrict__ bias, float* __restrict__ C,
    int M, int K, int F, int do_relu,
    float (*As)[BM], float (*Ws)[BN])
{
    const int tid = threadIdx.x;
    const int tx = tid & 15;        // n: 4 cols each
    const int ty = tid >> 4;        // m: 8 rows each
    const int bm = bx * BM;
    const int bn = by * BN;

    const int am  = tid >> 3;       // A staging: row 0..31 (+32*it)
    const int akq = tid & 7;        // A staging: float4 index within 32-k row
    const int wr  = tid >> 4;       // W staging: row 0..15 (+16*it)
    const int wcq = tid & 15;       // W staging: float4 col

    float acc[8][4] = {};

    for (int k0 = 0; k0 < K; k0 += BK) {
        #pragma unroll
        for (int it = 0; it < 4; ++it) {
            int m = am + it * 32;
            int gm = bm + m;
            float4 a4 = make_float4(0.f, 0.f, 0.f, 0.f);
            if (gm < M)
                a4 = *(const float4*)&A[(size_t)gm * K + k0 + akq * 4];
            int msw = m ^ (akq << 3);
            As[akq * 4 + 0][msw] = a4.x;
            As[akq * 4 + 1][msw] = a4.y;
            As[akq * 4 + 2][msw] = a4.z;
            As[akq * 4 + 3][msw] = a4.w;
        }
        #pragma unroll
        for (int it = 0; it < 2; ++it) {
            int r = wr + it * 16;
            float4 w4 = *(const float4*)&W[(size_t)(k0 + r) * F + bn + wcq * 4];
            *(float4*)&Ws[r][wcq * 4] = w4;
        }
        __syncthreads();
        #pragma unroll
        for (int kk = 0; kk < BK; ++kk) {
            const float* ap = &As[kk][(ty * 8) ^ (((kk >> 2) & 7) << 3)];
            float4 a0 = *(const float4*)(ap);
            float4 a1 = *(const float4*)(ap + 4);
            float4 w4 = *(const float4*)&Ws[kk][tx * 4];
            float a[8] = {a0.x, a0.y, a0.z, a0.w, a1.x, a1.y, a1.z, a1.w};
            float w[4] = {w4.x, w4.y, w4.z, w4.w};
            #pragma unroll
            for (int i = 0; i < 8; ++i)
                #pragma unroll
                for (int j = 0; j < 4; ++j)
                    acc[i][j] = fmaf(a[i], w[j], acc[i][j]);
        }
        __syncthreads();
    }
    float4 b4 = *(const float4*)&bias[bn + tx * 4];
    #pragma unroll
    for (int i = 0; i < 8; ++i) {
        int m = bm + ty * 8 + i;
        if (m < M) {
            float4 v;
            v.x = acc[i][0] + b4.x;
            v.y = acc[i][1] + b4.y;
            v.z = acc[i][2] + b4.z;
            v.w = acc[i][3] + b4.w;
            if (do_relu) {
                v.x = fmaxf(v.x, 0.f); v.y = fmaxf(v.y, 0.f);
                v.z = fmaxf(v.z, 0.f); v.w = fmaxf(v.w, 0.f);
            }
            *(float4*)&C[(size_t)m * F + bn + tx * 4] = v;
        }
    }
}

__global__ __launch_bounds__(256, 4) void gemm_bias_act(
    const float* __restrict__ A, const float* __restrict__ W,
    const float* __restrict__ bias, float* __restrict__ C,
    int M, int K, int F, int do_relu)
{
    __shared__ float As[BK][BM];
    __shared__ float Ws[BK][BN];
    gemm_tile(blockIdx.x, blockIdx.y, A, W, bias, C, M, K, F, do_relu, As, Ws);
}

// ---------------- fused A: degree+rank (coherence-bound) || GEMM-L0-s (VALU-bound) ----
// block mapping interleaves 1 gemm : 4 degree so both cohorts are co-resident.
// deg layout: [0,N) = outdeg (row), [N,2N) = indeg (col)
__global__ __launch_bounds__(256, 4) void fusedA_kernel(
    const float* __restrict__ A, const float* __restrict__ W,
    const float* __restrict__ bias, float* __restrict__ C,
    int M, int K, int F,
    const int* __restrict__ row, const int* __restrict__ col,
    int* __restrict__ deg, int* __restrict__ rank_r, int* __restrict__ rank_c,
    int E, int N, int deg_blocks)
{
    __shared__ float As[BK][BM];
    __shared__ float Ws[BK][BN];
    int g = blockIdx.x / 5;
    int r = blockIdx.x % 5;
    if (r == 0) {
        gemm_tile(g % GXM, g / GXM, A, W, bias, C, M, K, F, 1, As, Ws);
    } else {
        int db = g * 4 + (r - 1);
        if (db < deg_blocks) {
            int e = db * 256 + threadIdx.x;
            if (e < E) {
                rank_r[e] = atomicAdd(&deg[row[e]], 1);
                rank_c[e] = atomicAdd(&deg[N + col[e]], 1);
            }
        }
    }
}

// ---------------- fused B: CSR scatter (fire-and-forget) || GEMM-L1-s ----------------
__global__ __launch_bounds__(256, 4) void fusedB_kernel(
    const float* __restrict__ A, const float* __restrict__ W,
    const float* __restrict__ bias, float* __restrict__ C,
    int M, int K, int F,
    const int* __restrict__ row, const int* __restrict__ col,
    const int* __restrict__ rank_r, const int* __restrict__ rank_c,
    const float* __restrict__ outinv, const float* __restrict__ ininv,
    const int* __restrict__ offs, int2* __restrict__ csr,
    int E, int N, int csr_blocks)
{
    __shared__ float As[BK][BM];
    __shared__ float Ws[BK][BN];
    int g = blockIdx.x / 5;
    int r = blockIdx.x % 5;
    if (r == 0) {
        gemm_tile(g % GXM, g / GXM, A, W, bias, C, M, K, F, 1, As, Ws);
    } else {
        int db = g * 4 + (r - 1);
        if (db < csr_blocks) {
            int e = db * 256 + threadIdx.x;
            if (e < E) {
                int rr = row[e], cc = col[e];
                float w = outinv[rr] * ininv[cc];
                int wb = __float_as_int(w);
                csr[offs[rr] + rank_r[e]]     = make_int2(cc, wb);
                csr[offs[N + cc] + rank_c[e]] = make_int2(rr, wb);
            }
        }
    }
}

// ---------------- fused C: GEMM-L2-s || GEMM-L0-t (independent GEMMs) ----------------
// 1:2 interleave (782 L2-s blocks : 1564 L0-t blocks).
__global__ __launch_bounds__(256, 4) void fusedC_kernel(
    const float* __restrict__ A0, const float* __restrict__ W0,
    const float* __restrict__ b0, float* __restrict__ C0, int K0, int F0, int relu0,
    const float* __restrict__ A1, const float* __restrict__ W1,
    const float* __restrict__ b1, float* __restrict__ C1, int K1, int F1, int relu1,
    int M)
{
    __shared__ float As[BK][BM];
    __shared__ float Ws[BK][BN];
    int g = blockIdx.x / 3;
    int r = blockIdx.x % 3;
    if (r == 0) {
        gemm_tile(g % GXM, g / GXM, A0, W0, b0, C0, M, K0, F0, relu0, As, Ws);
    } else {
        int idx = g * 2 + (r - 1);
        gemm_tile(idx % GXM, idx / GXM, A1, W1, b1, C1, M, K1, F1, relu1, As, Ws);
    }
}

// ---------------- degree helpers ----------------
__global__ void zero_int_kernel(int* __restrict__ p, int n) {
    int i = blockIdx.x * blockDim.x + threadIdx.x;
    if (i < n) p[i] = 0;
}

// ---------------- scan (blocks 0..sb-1) fused with inv (blocks sb..) ----------------
__global__ __launch_bounds__(256) void scan_inv_kernel(
    const int* __restrict__ in, int* __restrict__ out,
    int* __restrict__ blocksums, int n2,          // scan over n2 = 2N
    float* __restrict__ outinv, float* __restrict__ ininv,
    float* __restrict__ wself, int n, int scan_blocks)
{
    int tid = threadIdx.x;
    if ((int)blockIdx.x < scan_blocks) {
        __shared__ int tmp[256];
        int gid = blockIdx.x * 256 + tid;
        int v = (gid < n2) ? in[gid] : 0;
        tmp[tid] = v;
        __syncthreads();
        for (int off = 1; off < 256; off <<= 1) {
            int t = (tid >= off) ? tmp[tid - off] : 0;
            __syncthreads();
            tmp[tid] += t;
            __syncthreads();
        }
        if (gid < n2) out[gid] = tmp[tid] - v;   // exclusive
        if (tid == 255) blocksums[blockIdx.x] = tmp[255];
    } else {
        int i = ((int)blockIdx.x - scan_blocks) * 256 + tid;
        if (i < n) {
            float oi = rsqrtf((float)(in[i] + 1));       // +1 self-loop
            float ii = rsqrtf((float)(in[n + i] + 1));
            outinv[i] = oi;
            ininv[i] = ii;
            wself[i] = oi * ii;
        }
    }
}

__global__ __launch_bounds__(1024) void scan_sums_kernel(int* __restrict__ blocksums, int nb) {
    __shared__ int tmp[1024];
    int tid = threadIdx.x;
    int v = (tid < nb) ? blocksums[tid] : 0;
    tmp[tid] = v;
    __syncthreads();
    for (int off = 1; off < 1024; off <<= 1) {
        int t = (tid >= off) ? tmp[tid - off] : 0;
        __syncthreads();
        tmp[tid] += t;
        __syncthreads();
    }
    if (tid < nb) blocksums[tid] = tmp[tid] - v;  // exclusive block offsets
}

__global__ void add_offsets_kernel(int* __restrict__ out, const int* __restrict__ blocksums, int n) {
    int gid = blockIdx.x * 256 + threadIdx.x;
    if (gid < n) out[gid] += blocksums[blockIdx.x];
}

// ---------------- fused conv round: gather + self-loop + residual ----------------
// wave (64 lanes) per output node; lanes = feature dim.
// 16-deep software pipeline (mean degree = 16): 16 independent gathers in flight
// per wave. Tail by predication (clamped index = cached re-read, weight zeroed).
#define DEPTH 16
__global__ __launch_bounds__(256) void conv_gather_kernel(
    const int* __restrict__ offs, const int* __restrict__ deg,
    const int2* __restrict__ csr, const float* __restrict__ wself,
    const float* __restrict__ s_old, const float* __restrict__ t_old,
    float* __restrict__ s_new, float* __restrict__ t_new,
    const float* __restrict__ conv_w, int k, int N)
{
    int wid = (int)((blockIdx.x * blockDim.x + threadIdx.x) >> 6);
    int lane = threadIdx.x & 63;
    if (wid >= 2 * N) return;
    int side = (wid >= N) ? 1 : 0;
    int n = side ? wid - N : wid;
    const float* other = side ? s_old : t_old;
    const float* self  = side ? t_old : s_old;
    float* out         = side ? t_new : s_new;
    float coef = conv_w[2 * k + side];

    int start = offs[wid];
    int d     = deg[wid];
    start = __builtin_amdgcn_readfirstlane(start);
    d     = __builtin_amdgcn_readfirstlane(d);
    int end = start + d;

    const unsigned long long* csr8 = (const unsigned long long*)csr;

    float acc[DEPTH];
    acc[0] = wself[n] * other[(size_t)n * 64 + lane];
    #pragma unroll
    for (int u = 1; u < DEPTH; ++u) acc[u] = 0.f;

    for (int p = start; p < end; p += DEPTH) {
        unsigned long long e[DEPTH];
        #pragma unroll
        for (int u = 0; u < DEPTH; ++u) {
            int q = p + u;
            q = (q < end) ? q : (end - 1);        // clamp: harmless cached re-read
            e[u] = __builtin_nontemporal_load(&csr8[q]);
        }
        #pragma unroll
        for (int u = 0; u < DEPTH; ++u) {
            float f = other[(size_t)(unsigned int)e[u] * 64 + lane];
            float w = (p + u < end) ? __int_as_float((int)(e[u] >> 32)) : 0.f;
            acc[u] = fmaf(w, f, acc[u]);
        }
    }

    #pragma unroll
    for (int s = DEPTH / 2; s >= 1; s >>= 1)
        #pragma unroll
        for (int u = 0; u < s; ++u) acc[u] += acc[u + s];

    size_t off = (size_t)n * 64 + lane;
    out[off] = fmaf(coef, acc[0], self[off]);
}

extern "C" void kernel_launch(void* const* d_in, const int* in_sizes, int n_in,
                              void* d_out, int out_size, void* d_ws, size_t ws_size,
                              hipStream_t stream) {
    const int N = N_NODES;
    const int E = N_EDGES;

    const float* s_in  = (const float*)d_in[0];
    const float* t_in  = (const float*)d_in[1];
    const int*   ei    = (const int*)d_in[2];
    const int*   row   = ei;
    const int*   col   = ei + E;
    const float* Ws0 = (const float*)d_in[3];
    const float* bs0 = (const float*)d_in[4];
    const float* Wt0 = (const float*)d_in[5];
    const float* bt0 = (const float*)d_in[6];
    const float* Ws1 = (const float*)d_in[7];
    const float* bs1 = (const float*)d_in[8];
    const float* Wt1 = (const float*)d_in[9];
    const float* bt1 = (const float*)d_in[10];
    const float* Ws2 = (const float*)d_in[11];
    const float* bs2 = (const float*)d_in[12];
    const float* Wt2 = (const float*)d_in[13];
    const float* bt2 = (const float*)d_in[14];
    const float* conv_w = (const float*)d_in[15];

    float* out_s = (float*)d_out;
    float* out_t = (float*)d_out + (size_t)N * DIM_OUT;

    // workspace layout (4-byte units)
    float* ws = (float*)d_ws;
    float* H1 = ws;                                   // N*128 (later S1/T1)
    float* H2 = ws + (size_t)N * DIM_HID;             // N*128
    float* S0 = ws + 2 * (size_t)N * DIM_HID;         // N*64
    float* T0 = S0 + (size_t)N * DIM_OUT;             // N*64
    float* S1 = H1;                                   // alias (free after MLPs)
    float* T1 = H1 + (size_t)N * DIM_OUT;
    int2*  CSR    = (int2*)(T0 + (size_t)N * DIM_OUT);   // 2E int2
    float* OUTINV = (float*)(CSR + 2 * (size_t)E);       // N
    float* ININV  = OUTINV + N;                          // N
    float* WSELF  = ININV + N;                           // N
    int*   DEG    = (int*)(WSELF + N);                   // 2N
    int*   OFFS   = DEG + 2 * N;                         // 2N (segment starts)
    int*   BSUMS  = OFFS + 2 * N;                        // ~1024
    // RANK arrays alias S0/T0: produced in fusedA, consumed in fusedB, dead
    // before fusedC writes S0.
    int*   RANKR  = (int*)S0;                            // E
    int*   RANKC  = RANKR + E;                           // E

    const int twoN = 2 * N;
    const int scan_blocks = (twoN + 255) / 256;          // 782
    const int inv_blocks  = (N + 255) / 256;             // 391
    const int edge_blocks = (E + 255) / 256;             // 6250
    const int gemm_blocks = GXM * (DIM_HID / BN);        // 1564
    const int fused_blocks = gemm_blocks * 5;            // 1:4 interleave

    // ---- zero degree counters ----
    zero_int_kernel<<<(twoN + 255) / 256, 256, 0, stream>>>(DEG, twoN);

    // ---- fusedA: degree+rank || GEMM-L0-s ----
    fusedA_kernel<<<fused_blocks, 256, 0, stream>>>(
        s_in, Ws0, bs0, H2, N, DIM_IN, DIM_HID,
        row, col, DEG, RANKR, RANKC, E, N, edge_blocks);

    // ---- scan of DEG -> OFFS (block-local) fused with inv ----
    scan_inv_kernel<<<scan_blocks + inv_blocks, 256, 0, stream>>>(
        DEG, OFFS, BSUMS, twoN, OUTINV, ININV, WSELF, N, scan_blocks);
    scan_sums_kernel<<<1, 1024, 0, stream>>>(BSUMS, scan_blocks);
    add_offsets_kernel<<<scan_blocks, 256, 0, stream>>>(OFFS, BSUMS, twoN);

    // ---- fusedB: CSR scatter || GEMM-L1-s ----
    fusedB_kernel<<<fused_blocks, 256, 0, stream>>>(
        H2, Ws1, bs1, H1, N, DIM_HID, DIM_HID,
        row, col, RANKR, RANKC, OUTINV, ININV, OFFS, CSR, E, N, edge_blocks);

    // ---- fusedC: GEMM-L2-s || GEMM-L0-t ----
    fusedC_kernel<<<GXM * 3, 256, 0, stream>>>(
        H1, Ws2, bs2, S0, DIM_HID, DIM_OUT, 0,
        t_in, Wt0, bt0, H2, DIM_IN, DIM_HID, 1,
        N);

    // ---- remaining t-path MLPs ----
    dim3 blk(256);
    dim3 g1(GXM, DIM_HID / BN);
    dim3 g3(GXM, DIM_OUT / BN);
    gemm_bias_act<<<g1, blk, 0, stream>>>(H2, Wt1, bt1, H1, N, DIM_HID, DIM_HID, 1);
    gemm_bias_act<<<g3, blk, 0, stream>>>(H1, Wt2, bt2, T0, N, DIM_HID, DIM_OUT, 0);

    // ---- 3 conv rounds, wave-per-node gather ----
    const int gather_blocks = (twoN * 64 + 255) / 256;   // 4 waves/block
    conv_gather_kernel<<<gather_blocks, 256, 0, stream>>>(OFFS, DEG, CSR, WSELF, S0, T0, S1, T1, conv_w, 0, N);
    conv_gather_kernel<<<gather_blocks, 256, 0, stream>>>(OFFS, DEG, CSR, WSELF, S1, T1, S0, T0, conv_w, 1, N);
    conv_gather_kernel<<<gather_blocks, 256, 0, stream>>>(OFFS, DEG, CSR, WSELF, S0, T0, out_s, out_t, conv_w, 2, N);
}